// Round 4
// baseline (538.385 us; speedup 1.0000x reference)
//
#include <hip/hip_runtime.h>

// CRF-RNN (C=2) on 56x56, all 10 iterations in ONE kernel (plain launch, all
// blocks provably co-resident: 392 blocks x 128 thr, 25KB LDS -> ~6 blocks/CU
// capacity, so the spin barrier cannot starve).
//   s = sigmoid(q1-q0); per iter: t_sp = K_sp@s, t_bl = K_bl@s built on the fly;
//   d = (2u-1) - alpha - beta*t_sp/n_sp - gamma*t_bl/n_bl;  s = sigmoid(d).
// Norms are s-independent: computed at iter 0, reciprocals kept in registers.
// Cross-iteration state: s[3136] double-buffered in ws. Grid barrier: counter
// in ws (zeroed per launch via hipMemsetAsync), release/acquire fences on ALL
// threads, s re-staged into LDS after each barrier so the hot loop is LDS-only.

namespace {

constexpr int NPIX  = 3136;
constexpr int WIMG  = 56;
constexpr int LPJ   = 16;             // lanes cooperating per j
constexpr int PER   = NPIX / LPJ;     // 196 contiguous i's per lane
constexpr int QUADS = PER / 4;        // 49 float4 steps
constexpr int JPB   = 8;              // j-pixels per block
constexpr int NBLK  = NPIX / JPB;     // 392 blocks
constexpr int NTHR  = JPB * LPJ;      // 128 threads

constexpr float LOG2E = 1.4426950408889634f;
constexpr float C1 = -LOG2E / 18.0f;      // spatial:  exp2(r2*C1)
constexpr float C2 = -LOG2E / 51200.0f;   // bilateral spatial term
constexpr float C3 = -LOG2E / 6.0f;       // bilateral intensity term

template <bool FIRST>
__device__ __forceinline__ void pair_pass(
    const float4* s4, const float4* g4,   // LDS
    int q0, int x0, int y0, float xj, float yj, float gj,
    float& tsp_o, float& tbl_o, float& nsp_o, float& nbl_o)
{
    float tsp = 0.f, tbl = 0.f, nsp = 0.f, nbl = 0.f;
    float xcur = (float)x0;           // x of quad base (multiple of 4)
    float dy   = (float)y0 - yj;
    float dy2  = dy * dy;
    for (int q = 0; q < QUADS; ++q) {
        const float4 sv = s4[q0 + q];
        const float4 gv = g4[q0 + q];
        const float dxb = xcur - xj;
#pragma unroll
        for (int e = 0; e < 4; ++e) {
            const float se = ((const float*)&sv)[e];
            const float ge = ((const float*)&gv)[e];
            const float dx = dxb + (float)e;
            const float r2 = fmaf(dx, dx, dy2);
            const float dg = ge - gj;
            const float esp = __builtin_amdgcn_exp2f(r2 * C1);
            const float ebl = __builtin_amdgcn_exp2f(fmaf(dg * C3, dg, r2 * C2));
            tsp = fmaf(se, esp, tsp);
            tbl = fmaf(se, ebl, tbl);
            if (FIRST) { nsp += esp; nbl += ebl; }
        }
        xcur += 4.0f;
        if (xcur >= 56.0f) { xcur -= 56.0f; dy += 1.0f; dy2 = dy * dy; }
    }
    tsp_o = tsp; tbl_o = tbl;
    if (FIRST) { nsp_o = nsp; nbl_o = nbl; }
}

#define REDUCE16(v) \
    { v += __shfl_xor(v, 1); v += __shfl_xor(v, 2); \
      v += __shfl_xor(v, 4); v += __shfl_xor(v, 8); }

// Grid barrier: release fence on EVERY thread, one arrival add per block,
// spin on EVERY thread, acquire fence on EVERY thread. Cumulative targets.
__device__ __forceinline__ void grid_barrier(unsigned* bar, unsigned target) {
    __threadfence();                       // release (agent): wb toward coherence
    __syncthreads();                       // whole block's stores fenced
    if (threadIdx.x == 0)
        __hip_atomic_fetch_add(bar, 1u, __ATOMIC_RELEASE,
                               __HIP_MEMORY_SCOPE_AGENT);
    while (__hip_atomic_load(bar, __ATOMIC_RELAXED,
                             __HIP_MEMORY_SCOPE_AGENT) < target)
        __builtin_amdgcn_s_sleep(1);
    __threadfence();                       // acquire (agent): invalidate stale
    __syncthreads();
}

__global__ __launch_bounds__(NTHR) void crf_all(
    const float* __restrict__ inp,
    const float* __restrict__ spw, const float* __restrict__ blw,
    const float* __restrict__ cmw,
    float* s0, float* s1, unsigned* bar,
    float* __restrict__ out)
{
    __shared__ float4 s_sh[NPIX / 4];     // current s, re-staged per iteration
    __shared__ float4 g_sh[NPIX / 4];     // gray values (iteration-invariant)

    const int t   = threadIdx.x;
    const int sub = t & (LPJ - 1);
    const int j   = blockIdx.x * JPB + (t >> 4);

    const float xj = (float)(j % WIMG);
    const float yj = (float)(j / WIMG);
    const float uj = inp[j];
    const float gj = inp[NPIX + j] * 255.0f;

    // collapse the 2x2 weight matrices to 3 scalars
    const float e0 = cmw[2] - cmw[0];
    const float e1 = cmw[3] - cmw[1];
    const float alpha = e0 * (spw[0] + blw[0]) + e1 * (spw[2] + blw[2]);
    const float beta  = e0 * (spw[1] - spw[0]) + e1 * (spw[3] - spw[2]);
    const float gamma = e0 * (blw[1] - blw[0]) + e1 * (blw[3] - blw[2]);

    const int i0 = sub * PER;
    const int y0 = i0 / WIMG;
    const int x0 = i0 - y0 * WIMG;
    const int q0 = sub * QUADS;

    // stage u (as iter-0 s) and g*255 into LDS
    {
        const float4* u4 = (const float4*)inp;
        const float4* gg = (const float4*)(inp + NPIX);
        for (int m = t; m < NPIX / 4; m += NTHR) {
            s_sh[m] = u4[m];
            float4 g = gg[m];
            g.x *= 255.0f; g.y *= 255.0f; g.z *= 255.0f; g.w *= 255.0f;
            g_sh[m] = g;
        }
    }
    __syncthreads();

    // ---- iteration 0: s = u (unaries), also accumulates norms
    float tsp, tbl, nsp, nbl;
    pair_pass<true>(s_sh, g_sh, q0, x0, y0, xj, yj, gj, tsp, tbl, nsp, nbl);
    REDUCE16(tsp); REDUCE16(tbl); REDUCE16(nsp); REDUCE16(nbl);
    const float rnsp = 1.0f / nsp;
    const float rnbl = 1.0f / nbl;
    const float base = 2.0f * uj - 1.0f - alpha;

    float d = base - beta * (tsp * rnsp) - gamma * (tbl * rnbl);
    float s = 1.0f / (1.0f + __builtin_amdgcn_exp2f(-d * LOG2E));
    if (sub == 0) s0[j] = s;
    unsigned tgt = NBLK;
    grid_barrier(bar, tgt);

    // ---- iterations 1..9
    float dum0, dum1;
    for (int k = 1; k < 10; ++k) {
        // re-stage s from the buffer published by the previous barrier
        const float4* src = (k & 1) ? (const float4*)s0 : (const float4*)s1;
        for (int m = t; m < NPIX / 4; m += NTHR) s_sh[m] = src[m];
        __syncthreads();

        pair_pass<false>(s_sh, g_sh, q0, x0, y0, xj, yj, gj, tsp, tbl, dum0, dum1);
        REDUCE16(tsp); REDUCE16(tbl);
        d = base - beta * (tsp * rnsp) - gamma * (tbl * rnbl);
        s = 1.0f / (1.0f + __builtin_amdgcn_exp2f(-d * LOG2E));
        if (k < 9) {
            float* dst = (k & 1) ? s1 : s0;
            if (sub == 0) dst[j] = s;
            tgt += NBLK;
            grid_barrier(bar, tgt);
        } else {
            if (sub == 0) out[j] = s;     // softmax(q)[1] = sigmoid(d)
        }
    }
}

}  // namespace

extern "C" void kernel_launch(void* const* d_in, const int* in_sizes, int n_in,
                              void* d_out, int out_size, void* d_ws, size_t ws_size,
                              hipStream_t stream) {
    const float* inp = (const float*)d_in[0];
    const float* spw = (const float*)d_in[1];
    const float* blw = (const float*)d_in[2];
    const float* cmw = (const float*)d_in[3];
    float* s0 = (float*)d_ws;
    float* s1 = s0 + NPIX;
    unsigned* bar = (unsigned*)((char*)d_ws + 25600);  // past s0/s1, own line
    float* out = (float*)d_out;

    hipMemsetAsync(bar, 0, sizeof(unsigned), stream);
    crf_all<<<dim3(NBLK), dim3(NTHR), 0, stream>>>(inp, spw, blw, cmw,
                                                   s0, s1, bar, out);
}

// Round 5
// 200.970 us; speedup vs baseline: 2.6789x; 2.6789x over previous
//
#include <hip/hip_runtime.h>

// CRF-RNN (C=2) on 56x56, all 10 iterations in ONE kernel, plain launch.
// 392 blocks x 128 thr (2 waves), 25KB LDS -> all blocks co-resident (~6/CU
// capacity), so the spin barrier cannot starve.
//
// Math: s = sigmoid(q1-q0); per iter t_sp=K_sp@s, t_bl=K_bl@s built on the fly
// (shared r^2); d = (2u-1) - alpha - beta*t_sp/n_sp - gamma*t_bl/n_bl.
// Norms are s-independent: iter-0 computes them, reciprocals stay in registers.
//
// Barrier redesign vs previous round (57us/barrier -> target ~2us):
//  - wave0 is the only wave touching global s-state (publish 8 floats, acquire,
//    restage 12.5KB into LDS); wave1 is LDS-only -> no fences, just s_barrier.
//  - hierarchical arrivals: 8 padded group counters (49 release-adds each),
//    8 leaders acquire + release-add one root counter.
//  - one poller wave per block on root, s_sleep(8) backoff; scoped acquire
//    loads instead of cache-wide __threadfence on every wave.

namespace {

constexpr int NPIX  = 3136;
constexpr int WIMG  = 56;
constexpr int LPJ   = 16;             // lanes cooperating per j
constexpr int PER   = NPIX / LPJ;     // 196 contiguous i's per lane
constexpr int QUADS = PER / 4;        // 49 float4 steps
constexpr int JPB   = 8;              // j-pixels per block
constexpr int NBLK  = NPIX / JPB;     // 392 blocks
constexpr int NTHR  = JPB * LPJ;      // 128 threads
constexpr int NGRP  = 8;
constexpr int GSZ   = NBLK / NGRP;    // 49 blocks per arrival group
constexpr int CPAD  = 64;             // u32 stride between counters (256B)

constexpr float LOG2E = 1.4426950408889634f;
constexpr float C1 = -LOG2E / 18.0f;      // spatial:  exp2(r2*C1)
constexpr float C2 = -LOG2E / 51200.0f;   // bilateral spatial term
constexpr float C3 = -LOG2E / 6.0f;       // bilateral intensity term

template <bool FIRST>
__device__ __forceinline__ void pair_pass(
    const float4* s4, const float4* g4,   // LDS
    int q0, int x0, int y0, float xj, float yj, float gj,
    float& tsp_o, float& tbl_o, float& nsp_o, float& nbl_o)
{
    float tsp = 0.f, tbl = 0.f, nsp = 0.f, nbl = 0.f;
    float xcur = (float)x0;           // x of quad base (multiple of 4)
    float dy   = (float)y0 - yj;
    float dy2  = dy * dy;
    for (int q = 0; q < QUADS; ++q) {
        const float4 sv = s4[q0 + q];
        const float4 gv = g4[q0 + q];
        const float dxb = xcur - xj;
#pragma unroll
        for (int e = 0; e < 4; ++e) {
            const float se = ((const float*)&sv)[e];
            const float ge = ((const float*)&gv)[e];
            const float dx = dxb + (float)e;
            const float r2 = fmaf(dx, dx, dy2);
            const float dg = ge - gj;
            const float esp = __builtin_amdgcn_exp2f(r2 * C1);
            const float ebl = __builtin_amdgcn_exp2f(fmaf(dg * C3, dg, r2 * C2));
            tsp = fmaf(se, esp, tsp);
            tbl = fmaf(se, ebl, tbl);
            if (FIRST) { nsp += esp; nbl += ebl; }
        }
        xcur += 4.0f;
        if (xcur >= 56.0f) { xcur -= 56.0f; dy += 1.0f; dy2 = dy * dy; }
    }
    tsp_o = tsp; tbl_o = tbl;
    if (FIRST) { nsp_o = nsp; nbl_o = nbl; }
}

#define REDUCE16(v) \
    { v += __shfl_xor(v, 1); v += __shfl_xor(v, 2); \
      v += __shfl_xor(v, 4); v += __shfl_xor(v, 8); }

// Publish this block's 8 s-values, grid-barrier, restage fresh s into LDS.
// buf: global s buffer for this iteration (written then re-read).
// it: 1-based barrier index (cumulative counter targets).
__device__ __forceinline__ void publish_sync_restage(
    int t, int bid, float s, unsigned it,
    float* buf, float4* s_sh, float* s_out_lds, unsigned* cnt)
{
    if ((t & (LPJ - 1)) == 0) s_out_lds[t >> 4] = s;   // leaders -> LDS
    __syncthreads();                                    // also: pair_pass done
    if (t < 64) {                                       // comm wave only
        if (t < JPB) buf[bid * JPB + t] = s_out_lds[t]; // publish (wave0 store)
        unsigned* gc   = cnt + (bid & (NGRP - 1)) * CPAD;
        unsigned* root = cnt + NGRP * CPAD;
        if (t == 0) {
            // release: drains wave0's vmem + L2 writeback, then arrival add
            __hip_atomic_fetch_add(gc, 1u, __ATOMIC_RELEASE,
                                   __HIP_MEMORY_SCOPE_AGENT);
            if (bid < NGRP) {                           // group leader block
                while (__hip_atomic_load(gc, __ATOMIC_RELAXED,
                                         __HIP_MEMORY_SCOPE_AGENT) < GSZ * it)
                    __builtin_amdgcn_s_sleep(2);
                (void)__hip_atomic_load(gc, __ATOMIC_ACQUIRE,
                                        __HIP_MEMORY_SCOPE_AGENT);
                __hip_atomic_fetch_add(root, 1u, __ATOMIC_RELEASE,
                                       __HIP_MEMORY_SCOPE_AGENT);
            }
        }
        // whole wave0 polls root (uniform address -> 1 load per wave)
        while (__hip_atomic_load(root, __ATOMIC_RELAXED,
                                 __HIP_MEMORY_SCOPE_AGENT) < NGRP * it)
            __builtin_amdgcn_s_sleep(8);
        (void)__hip_atomic_load(root, __ATOMIC_ACQUIRE,
                                __HIP_MEMORY_SCOPE_AGENT);
        // restage fresh s into LDS (wave0's plain loads, ordered by acquire)
        const float4* src = (const float4*)buf;
        for (int m = t; m < NPIX / 4; m += 64) s_sh[m] = src[m];
    }
    __syncthreads();                                    // compute waves resume
}

__global__ __launch_bounds__(NTHR) void crf_all(
    const float* __restrict__ inp,
    const float* __restrict__ spw, const float* __restrict__ blw,
    const float* __restrict__ cmw,
    float* s0, float* s1, unsigned* cnt,
    float* __restrict__ out)
{
    __shared__ float4 s_sh[NPIX / 4];     // current s (restaged per iteration)
    __shared__ float4 g_sh[NPIX / 4];     // gray*255 (iteration-invariant)
    __shared__ float  s_out[JPB];

    const int t   = threadIdx.x;
    const int bid = blockIdx.x;
    const int sub = t & (LPJ - 1);
    const int j   = bid * JPB + (t >> 4);

    const float xj = (float)(j % WIMG);
    const float yj = (float)(j / WIMG);
    const float uj = inp[j];
    const float gj = inp[NPIX + j] * 255.0f;

    // collapse the 2x2 weight matrices to 3 scalars
    const float e0 = cmw[2] - cmw[0];
    const float e1 = cmw[3] - cmw[1];
    const float alpha = e0 * (spw[0] + blw[0]) + e1 * (spw[2] + blw[2]);
    const float beta  = e0 * (spw[1] - spw[0]) + e1 * (spw[3] - spw[2]);
    const float gamma = e0 * (blw[1] - blw[0]) + e1 * (blw[3] - blw[2]);

    const int i0 = sub * PER;
    const int y0 = i0 / WIMG;
    const int x0 = i0 - y0 * WIMG;
    const int q0 = sub * QUADS;

    // stage u (iter-0 s) and g*255 into LDS
    {
        const float4* u4 = (const float4*)inp;
        const float4* gg = (const float4*)(inp + NPIX);
        for (int m = t; m < NPIX / 4; m += NTHR) {
            s_sh[m] = u4[m];
            float4 g = gg[m];
            g.x *= 255.0f; g.y *= 255.0f; g.z *= 255.0f; g.w *= 255.0f;
            g_sh[m] = g;
        }
    }
    __syncthreads();

    // ---- iteration 0: s = u (unaries), also accumulates norms
    float tsp, tbl, nsp, nbl;
    pair_pass<true>(s_sh, g_sh, q0, x0, y0, xj, yj, gj, tsp, tbl, nsp, nbl);
    REDUCE16(tsp); REDUCE16(tbl); REDUCE16(nsp); REDUCE16(nbl);
    const float rnsp = 1.0f / nsp;
    const float rnbl = 1.0f / nbl;
    const float base = 2.0f * uj - 1.0f - alpha;

    float d = base - beta * (tsp * rnsp) - gamma * (tbl * rnbl);
    float s = 1.0f / (1.0f + __builtin_amdgcn_exp2f(-d * LOG2E));
    publish_sync_restage(t, bid, s, 1u, s0, s_sh, s_out, cnt);

    // ---- iterations 1..9
    float dum0, dum1;
    for (int k = 1; k < 10; ++k) {
        pair_pass<false>(s_sh, g_sh, q0, x0, y0, xj, yj, gj, tsp, tbl, dum0, dum1);
        REDUCE16(tsp); REDUCE16(tbl);
        d = base - beta * (tsp * rnsp) - gamma * (tbl * rnbl);
        s = 1.0f / (1.0f + __builtin_amdgcn_exp2f(-d * LOG2E));
        if (k < 9) {
            float* buf = (k & 1) ? s1 : s0;
            publish_sync_restage(t, bid, s, (unsigned)(k + 1), buf, s_sh, s_out, cnt);
        } else {
            if (sub == 0) out[j] = s;     // softmax(q)[1] = sigmoid(d)
        }
    }
}

}  // namespace

extern "C" void kernel_launch(void* const* d_in, const int* in_sizes, int n_in,
                              void* d_out, int out_size, void* d_ws, size_t ws_size,
                              hipStream_t stream) {
    const float* inp = (const float*)d_in[0];
    const float* spw = (const float*)d_in[1];
    const float* blw = (const float*)d_in[2];
    const float* cmw = (const float*)d_in[3];
    float* s0 = (float*)d_ws;
    float* s1 = s0 + NPIX;
    unsigned* cnt = (unsigned*)((char*)d_ws + 25600);  // 8 group ctrs + root, 256B-strided
    float* out = (float*)d_out;

    hipMemsetAsync(cnt, 0, (NGRP + 1) * CPAD * sizeof(unsigned), stream);
    crf_all<<<dim3(NBLK), dim3(NTHR), 0, stream>>>(inp, spw, blw, cmw,
                                                   s0, s1, cnt, out);
}

// Round 6
// 136.224 us; speedup vs baseline: 3.9522x; 1.4753x over previous
//
#include <hip/hip_runtime.h>

// CRF-RNN (C=2) on 56x56, all 10 iterations in ONE kernel, plain launch.
// 392 blocks x 128 thr (2 waves), 25KB LDS -> all blocks co-resident (~6/CU
// LDS capacity, 1.53 needed), so the spin barrier cannot starve.
//
// Math: s = sigmoid(q1-q0); per iter t_sp=K_sp@s, t_bl=K_bl@s built on the fly
// (shared r^2); d = (2u-1) - alpha - beta*t_sp/n_sp - gamma*t_bl/n_bl.
// Norms are s-independent: iter-0 computes them, reciprocals stay in registers.
//
// Barrier v3 (round5 was 18us/barrier -> target ~1.5us): agent-scope
// RELEASE/ACQUIRE on gfx950 emits buffer_wbl2 / buffer_inv (whole-L2
// writeback/invalidate) per block per barrier -- 784 L2 cache ops per sync.
// Replace ALL cross-block traffic with agent-scope RELAXED atomics: they
// execute at the LLC (sc1, past the non-coherent XCD L2s) and need NO cache
// maintenance. Ordering store->arrival via explicit s_waitcnt vmcnt(0)
// (store retires when data is at the LLC = globally visible).

namespace {

constexpr int NPIX  = 3136;
constexpr int WIMG  = 56;
constexpr int LPJ   = 16;             // lanes cooperating per j
constexpr int PER   = NPIX / LPJ;     // 196 contiguous i's per lane
constexpr int QUADS = PER / 4;        // 49 float4 steps
constexpr int JPB   = 8;              // j-pixels per block
constexpr int NBLK  = NPIX / JPB;     // 392 blocks
constexpr int NTHR  = JPB * LPJ;      // 128 threads
constexpr int NGRP  = 8;
constexpr int GSZ   = NBLK / NGRP;    // 49 blocks per arrival group
constexpr int CPAD  = 64;             // u32 stride between counters (256B)
constexpr int RST   = NPIX / 64;      // 49 restage loads per wave0 lane

constexpr float LOG2E = 1.4426950408889634f;
constexpr float C1 = -LOG2E / 18.0f;      // spatial:  exp2(r2*C1)
constexpr float C2 = -LOG2E / 51200.0f;   // bilateral spatial term
constexpr float C3 = -LOG2E / 6.0f;       // bilateral intensity term

template <bool FIRST>
__device__ __forceinline__ void pair_pass(
    const float4* s4, const float4* g4,   // LDS
    int q0, int x0, int y0, float xj, float yj, float gj,
    float& tsp_o, float& tbl_o, float& nsp_o, float& nbl_o)
{
    float tsp = 0.f, tbl = 0.f, nsp = 0.f, nbl = 0.f;
    float xcur = (float)x0;           // x of quad base (multiple of 4)
    float dy   = (float)y0 - yj;
    float dy2  = dy * dy;
    for (int q = 0; q < QUADS; ++q) {
        const float4 sv = s4[q0 + q];
        const float4 gv = g4[q0 + q];
        const float dxb = xcur - xj;
#pragma unroll
        for (int e = 0; e < 4; ++e) {
            const float se = ((const float*)&sv)[e];
            const float ge = ((const float*)&gv)[e];
            const float dx = dxb + (float)e;
            const float r2 = fmaf(dx, dx, dy2);
            const float dg = ge - gj;
            const float esp = __builtin_amdgcn_exp2f(r2 * C1);
            const float ebl = __builtin_amdgcn_exp2f(fmaf(dg * C3, dg, r2 * C2));
            tsp = fmaf(se, esp, tsp);
            tbl = fmaf(se, ebl, tbl);
            if (FIRST) { nsp += esp; nbl += ebl; }
        }
        xcur += 4.0f;
        if (xcur >= 56.0f) { xcur -= 56.0f; dy += 1.0f; dy2 = dy * dy; }
    }
    tsp_o = tsp; tbl_o = tbl;
    if (FIRST) { nsp_o = nsp; nbl_o = nbl; }
}

#define REDUCE16(v) \
    { v += __shfl_xor(v, 1); v += __shfl_xor(v, 2); \
      v += __shfl_xor(v, 4); v += __shfl_xor(v, 8); }

__device__ __forceinline__ unsigned ld_cnt(unsigned* p) {
    return __hip_atomic_load(p, __ATOMIC_RELAXED, __HIP_MEMORY_SCOPE_AGENT);
}

// Publish this block's 8 s-values, grid-barrier, restage fresh s into LDS.
// All cross-block traffic = agent-scope RELAXED atomics (LLC-coherent, no
// cache maintenance). it: 1-based barrier index (cumulative targets).
__device__ __forceinline__ void publish_sync_restage(
    int t, int bid, float s, unsigned it,
    float* buf, float4* s_sh, float* s_out_lds, unsigned* cnt)
{
    if ((t & (LPJ - 1)) == 0) s_out_lds[t >> 4] = s;   // leaders -> LDS
    __syncthreads();                                    // also: pair_pass done
    if (t < 64) {                                       // comm wave only
        if (t < JPB)
            __hip_atomic_store(&buf[bid * JPB + t], s_out_lds[t],
                               __ATOMIC_RELAXED, __HIP_MEMORY_SCOPE_AGENT);
        // stores globally visible (at LLC) before the arrival add:
        asm volatile("s_waitcnt vmcnt(0)" ::: "memory");
        unsigned* gc   = cnt + (bid & (NGRP - 1)) * CPAD;
        unsigned* root = cnt + NGRP * CPAD;
        if (t == 0) {
            __hip_atomic_fetch_add(gc, 1u, __ATOMIC_RELAXED,
                                   __HIP_MEMORY_SCOPE_AGENT);
            if (bid < NGRP) {                           // group leader block
                while (ld_cnt(gc) < GSZ * it)
                    __builtin_amdgcn_s_sleep(2);
                __hip_atomic_fetch_add(root, 1u, __ATOMIC_RELAXED,
                                       __HIP_MEMORY_SCOPE_AGENT);
            }
        }
        // whole wave0 polls root (uniform address -> 1 request per wave)
        while (ld_cnt(root) < NGRP * it)
            __builtin_amdgcn_s_sleep(8);
        asm volatile("" ::: "memory");
        // restage fresh s: 49 LLC loads batched into registers (all in flight)
        float tmp[RST];
#pragma unroll
        for (int q = 0; q < RST; ++q)
            tmp[q] = __hip_atomic_load(&buf[q * 64 + t], __ATOMIC_RELAXED,
                                       __HIP_MEMORY_SCOPE_AGENT);
        float* s_f = (float*)s_sh;
#pragma unroll
        for (int q = 0; q < RST; ++q) s_f[q * 64 + t] = tmp[q];
    }
    __syncthreads();                                    // compute waves resume
}

__global__ __launch_bounds__(NTHR) void crf_all(
    const float* __restrict__ inp,
    const float* __restrict__ spw, const float* __restrict__ blw,
    const float* __restrict__ cmw,
    float* s0, float* s1, unsigned* cnt,
    float* __restrict__ out)
{
    __shared__ float4 s_sh[NPIX / 4];     // current s (restaged per iteration)
    __shared__ float4 g_sh[NPIX / 4];     // gray*255 (iteration-invariant)
    __shared__ float  s_out[JPB];

    const int t   = threadIdx.x;
    const int bid = blockIdx.x;
    const int sub = t & (LPJ - 1);
    const int j   = bid * JPB + (t >> 4);

    const float xj = (float)(j % WIMG);
    const float yj = (float)(j / WIMG);
    const float uj = inp[j];
    const float gj = inp[NPIX + j] * 255.0f;

    // collapse the 2x2 weight matrices to 3 scalars
    const float e0 = cmw[2] - cmw[0];
    const float e1 = cmw[3] - cmw[1];
    const float alpha = e0 * (spw[0] + blw[0]) + e1 * (spw[2] + blw[2]);
    const float beta  = e0 * (spw[1] - spw[0]) + e1 * (spw[3] - spw[2]);
    const float gamma = e0 * (blw[1] - blw[0]) + e1 * (blw[3] - blw[2]);

    const int i0 = sub * PER;
    const int y0 = i0 / WIMG;
    const int x0 = i0 - y0 * WIMG;
    const int q0 = sub * QUADS;

    // stage u (iter-0 s) and g*255 into LDS
    {
        const float4* u4 = (const float4*)inp;
        const float4* gg = (const float4*)(inp + NPIX);
        for (int m = t; m < NPIX / 4; m += NTHR) {
            s_sh[m] = u4[m];
            float4 g = gg[m];
            g.x *= 255.0f; g.y *= 255.0f; g.z *= 255.0f; g.w *= 255.0f;
            g_sh[m] = g;
        }
    }
    __syncthreads();

    // ---- iteration 0: s = u (unaries), also accumulates norms
    float tsp, tbl, nsp, nbl;
    pair_pass<true>(s_sh, g_sh, q0, x0, y0, xj, yj, gj, tsp, tbl, nsp, nbl);
    REDUCE16(tsp); REDUCE16(tbl); REDUCE16(nsp); REDUCE16(nbl);
    const float rnsp = 1.0f / nsp;
    const float rnbl = 1.0f / nbl;
    const float base = 2.0f * uj - 1.0f - alpha;

    float d = base - beta * (tsp * rnsp) - gamma * (tbl * rnbl);
    float s = 1.0f / (1.0f + __builtin_amdgcn_exp2f(-d * LOG2E));
    publish_sync_restage(t, bid, s, 1u, s0, s_sh, s_out, cnt);

    // ---- iterations 1..9
    float dum0, dum1;
    for (int k = 1; k < 10; ++k) {
        pair_pass<false>(s_sh, g_sh, q0, x0, y0, xj, yj, gj, tsp, tbl, dum0, dum1);
        REDUCE16(tsp); REDUCE16(tbl);
        d = base - beta * (tsp * rnsp) - gamma * (tbl * rnbl);
        s = 1.0f / (1.0f + __builtin_amdgcn_exp2f(-d * LOG2E));
        if (k < 9) {
            float* buf = (k & 1) ? s1 : s0;
            publish_sync_restage(t, bid, s, (unsigned)(k + 1), buf, s_sh, s_out, cnt);
        } else {
            if (sub == 0) out[j] = s;     // softmax(q)[1] = sigmoid(d)
        }
    }
}

}  // namespace

extern "C" void kernel_launch(void* const* d_in, const int* in_sizes, int n_in,
                              void* d_out, int out_size, void* d_ws, size_t ws_size,
                              hipStream_t stream) {
    const float* inp = (const float*)d_in[0];
    const float* spw = (const float*)d_in[1];
    const float* blw = (const float*)d_in[2];
    const float* cmw = (const float*)d_in[3];
    float* s0 = (float*)d_ws;
    float* s1 = s0 + NPIX;
    unsigned* cnt = (unsigned*)((char*)d_ws + 25600);  // 8 group ctrs + root, 256B-strided
    float* out = (float*)d_out;

    hipMemsetAsync(cnt, 0, (NGRP + 1) * CPAD * sizeof(unsigned), stream);
    crf_all<<<dim3(NBLK), dim3(NTHR), 0, stream>>>(inp, spw, blw, cmw,
                                                   s0, s1, cnt, out);
}

// Round 7
// 125.880 us; speedup vs baseline: 4.2770x; 1.0822x over previous
//
#include <hip/hip_runtime.h>

// CRF-RNN (C=2) on 56x56, 10 iterations in ONE kernel, plain launch.
// 392 blocks x 128 thr (2 waves), ~30KB LDS -> 5 blocks/CU capacity, all
// blocks co-resident, so the spin barrier cannot starve.
//
// Math: s = sigmoid(q1-q0); per iter t_sp=K_sp@s, t_bl=K_bl@s;
// d = (2u-1) - alpha - beta*t_sp/n_sp - gamma*t_bl/n_bl. Kernels factored
// separably: k_sp = wsy[row]*wsx[x], k_bl = wby[row]*wbx[x]*exp2(C3*dg^2);
// the geometric tables are iteration-invariant -> built once in LDS.
//
// Barrier v4: agent-RELAXED atomics only (LLC-coherent, no L2 maintenance).
// Arrival tree: 8 group counters <- 392 blocks; 8 leaders -> root; superleader
// polls root and fans out 8 per-group done-flags; every block polls its flag
// with lane 0 only. Restage: coalesced global_load_dwordx4 sc0 sc1 (L1/L2
// bypass -> LLC-fresh), 13 in flight, one vmcnt(0).

namespace {

constexpr int NPIX  = 3136;
constexpr int WIMG  = 56;
constexpr int LPJ   = 16;             // lanes cooperating per j
constexpr int JPB   = 8;              // j-pixels per block
constexpr int NBLK  = NPIX / JPB;     // 392 blocks
constexpr int NTHR  = JPB * LPJ;      // 128 threads
constexpr int NQ    = NPIX / 4;       // 784 quads
constexpr int SPAD  = 832;            // padded float4 count (13*64) for s bufs
constexpr int NGRP  = 8;
constexpr int GSZ   = NBLK / NGRP;    // 49
constexpr int CPAD  = 64;             // u32 stride between counters (256B)

constexpr float LOG2E = 1.4426950408889634f;
constexpr float C1 = -LOG2E / 18.0f;      // spatial:   exp2(C1*d^2)
constexpr float C2 = -LOG2E / 51200.0f;   // bilateral spatial factor
constexpr float C3 = -LOG2E / 6.0f;       // bilateral intensity factor

// Strided-quad pair pass: lane handles quads {sub, sub+16, ...} (49 total,
// uniform trip count). Per quad: 4-elem partials folded by row weights.
template <bool FIRST>
__device__ __forceinline__ void pair_pass(
    const float4* s4, const float4* g4,
    const float* wsx, const float* wbx,     // this j's rows: tbl + jl*56
    const float* wsy, const float* wby,
    int sub, float gj,
    float& tsp_o, float& tbl_o, float& nsp_o, float& nbl_o)
{
    float tsp = 0.f, tbl = 0.f, nsp = 0.f, nbl = 0.f;
    int mq  = sub;                       // global quad index
    int row = (sub >= 14) ? 1 : 0;       // quad row = mq/14
    int xq  = sub - 14 * row;            // quad col = mq%14
    for (int k = 0; k < 49; ++k) {
        const float4 sv = s4[mq];
        const float4 gv = g4[mq];
        const float4 wsv = *(const float4*)(wsx + xq * 4);
        const float4 wbv = *(const float4*)(wbx + xq * 4);
        float rS = 0.f, rB = 0.f, nS = 0.f, nB = 0.f;
#pragma unroll
        for (int e = 0; e < 4; ++e) {
            const float se = ((const float*)&sv)[e];
            const float ge = ((const float*)&gv)[e];
            const float ws = ((const float*)&wsv)[e];
            const float wb = ((const float*)&wbv)[e];
            const float dg = ge - gj;
            const float edg = __builtin_amdgcn_exp2f((dg * C3) * dg);
            rS = fmaf(ws, se, rS);
            const float p = wb * edg;
            rB = fmaf(p, se, rB);
            if (FIRST) { nS += ws; nB += p; }
        }
        const float wy = wsy[row], wb_r = wby[row];
        tsp = fmaf(wy, rS, tsp);
        tbl = fmaf(wb_r, rB, tbl);
        if (FIRST) { nsp = fmaf(wy, nS, nsp); nbl = fmaf(wb_r, nB, nbl); }
        mq += 16;
        xq += 2; row += 1;               // +16 quads = +1 row + 2 quads
        if (xq >= 14) { xq -= 14; row += 1; }
    }
    tsp_o = tsp; tbl_o = tbl;
    if (FIRST) { nsp_o = nsp; nbl_o = nbl; }
}

#define REDUCE16(v) \
    { v += __shfl_xor(v, 1); v += __shfl_xor(v, 2); \
      v += __shfl_xor(v, 4); v += __shfl_xor(v, 8); }

__device__ __forceinline__ unsigned ld_cnt(unsigned* p) {
    return __hip_atomic_load(p, __ATOMIC_RELAXED, __HIP_MEMORY_SCOPE_AGENT);
}

// Publish this block's 8 s-values, grid-barrier (doorbell tree), restage
// fresh s into LDS via coalesced LLC-bypass loads. it = 1-based barrier idx.
__device__ __forceinline__ void publish_sync_restage(
    int t, int bid, float s, unsigned it,
    float* buf, float4* s_sh, float* s_out_lds, unsigned* cnt)
{
    if ((t & (LPJ - 1)) == 0) s_out_lds[t >> 4] = s;   // j-leaders -> LDS
    __syncthreads();                                    // pair_pass done too
    if (t < 64) {                                       // comm wave only
        if (t < JPB)
            __hip_atomic_store(&buf[bid * JPB + t], s_out_lds[t],
                               __ATOMIC_RELAXED, __HIP_MEMORY_SCOPE_AGENT);
        // publish stores globally visible (at LLC) before arrival:
        asm volatile("s_waitcnt vmcnt(0)" ::: "memory");
        unsigned* gc   = cnt + (bid & (NGRP - 1)) * CPAD;
        unsigned* root = cnt + NGRP * CPAD;
        unsigned* flag = cnt + (NGRP + 1 + (bid & (NGRP - 1))) * CPAD;
        if (t == 0) {   // one lane; rest of wave is exec-masked (no ITS on CDNA)
            __hip_atomic_fetch_add(gc, 1u, __ATOMIC_RELAXED,
                                   __HIP_MEMORY_SCOPE_AGENT);
            if (bid < NGRP) {                           // group leader
                while (ld_cnt(gc) < GSZ * it) __builtin_amdgcn_s_sleep(2);
                __hip_atomic_fetch_add(root, 1u, __ATOMIC_RELAXED,
                                       __HIP_MEMORY_SCOPE_AGENT);
            }
            if (bid == NGRP) {                          // superleader (blk 8)
                while (ld_cnt(root) < NGRP * it) __builtin_amdgcn_s_sleep(2);
#pragma unroll
                for (int g = 0; g < NGRP; ++g)
                    __hip_atomic_store(cnt + (NGRP + 1 + g) * CPAD, it,
                                       __ATOMIC_RELAXED,
                                       __HIP_MEMORY_SCOPE_AGENT);
            }
            while (ld_cnt(flag) < it) __builtin_amdgcn_s_sleep(4);
        }
        asm volatile("" ::: "memory");                  // compiler barrier
        // restage: 13 coalesced 16B LLC-bypass loads per lane, all in flight
        const float4* src = (const float4*)buf;
        float4 vv[13];
#pragma unroll
        for (int qq = 0; qq < 13; ++qq)
            asm volatile("global_load_dwordx4 %0, %1, off sc0 sc1"
                         : "=&v"(vv[qq]) : "v"(src + qq * 64 + t));
        asm volatile("s_waitcnt vmcnt(0)" ::: "memory");
#pragma unroll
        for (int qq = 0; qq < 13; ++qq) s_sh[qq * 64 + t] = vv[qq];
    }
    __syncthreads();                                    // compute waves resume
}

__global__ __launch_bounds__(NTHR) void crf_all(
    const float* __restrict__ inp,
    const float* __restrict__ spw, const float* __restrict__ blw,
    const float* __restrict__ cmw,
    float* s0, float* s1, unsigned* cnt,
    float* __restrict__ out)
{
    __shared__ float4 s_sh[SPAD];         // current s (832: incl. restage pad)
    __shared__ float4 g_sh[NQ];           // gray*255 (iteration-invariant)
    __shared__ float  wsx_t[JPB * 56];    // exp2(C1*(xj-x')^2) per local j
    __shared__ float  wbx_t[JPB * 56];    // exp2(C2*(xj-x')^2)
    __shared__ float  wsy_t[56];          // exp2(C1*(yj-y')^2) (yj same all j)
    __shared__ float  wby_t[56];          // exp2(C2*(yj-y')^2)
    __shared__ float  s_out[JPB];

    const int t   = threadIdx.x;
    const int bid = blockIdx.x;
    const int sub = t & (LPJ - 1);
    const int jl  = t >> 4;
    const int j   = bid * JPB + jl;

    const int xj0 = (bid * JPB) % WIMG;   // 8 j's: same row, consecutive x
    const int yj  = (bid * JPB) / WIMG;
    const float uj = inp[j];
    const float gj = inp[NPIX + j] * 255.0f;

    // collapse the 2x2 weight matrices to 3 scalars
    const float e0 = cmw[2] - cmw[0];
    const float e1 = cmw[3] - cmw[1];
    const float alpha = e0 * (spw[0] + blw[0]) + e1 * (spw[2] + blw[2]);
    const float beta  = e0 * (spw[1] - spw[0]) + e1 * (spw[3] - spw[2]);
    const float gamma = e0 * (blw[1] - blw[0]) + e1 * (blw[3] - blw[2]);

    // build weight tables (iteration-invariant)
    for (int idx = t; idx < JPB * 56; idx += NTHR) {
        const int tjl = idx / 56, xp = idx - tjl * 56;
        const float dd = (float)(xj0 + tjl - xp);
        const float d2 = dd * dd;
        wsx_t[idx] = __builtin_amdgcn_exp2f(C1 * d2);
        wbx_t[idx] = __builtin_amdgcn_exp2f(C2 * d2);
    }
    if (t < 56) {
        const float dd = (float)(yj - t);
        const float d2 = dd * dd;
        wsy_t[t] = __builtin_amdgcn_exp2f(C1 * d2);
        wby_t[t] = __builtin_amdgcn_exp2f(C2 * d2);
    }
    // stage u (iter-0 s) and g*255 into LDS
    {
        const float4* u4 = (const float4*)inp;
        const float4* gg = (const float4*)(inp + NPIX);
        for (int m = t; m < NQ; m += NTHR) {
            s_sh[m] = u4[m];
            float4 g = gg[m];
            g.x *= 255.0f; g.y *= 255.0f; g.z *= 255.0f; g.w *= 255.0f;
            g_sh[m] = g;
        }
    }
    __syncthreads();

    const float* wsx = wsx_t + jl * 56;
    const float* wbx = wbx_t + jl * 56;

    // ---- iteration 0: s = u (unaries), also accumulates norms
    float tsp, tbl, nsp, nbl;
    pair_pass<true>(s_sh, g_sh, wsx, wbx, wsy_t, wby_t, sub, gj,
                    tsp, tbl, nsp, nbl);
    REDUCE16(tsp); REDUCE16(tbl); REDUCE16(nsp); REDUCE16(nbl);
    const float rnsp = 1.0f / nsp;
    const float rnbl = 1.0f / nbl;
    const float base = 2.0f * uj - 1.0f - alpha;

    float d = base - beta * (tsp * rnsp) - gamma * (tbl * rnbl);
    float s = 1.0f / (1.0f + __builtin_amdgcn_exp2f(-d * LOG2E));
    publish_sync_restage(t, bid, s, 1u, s0, s_sh, s_out, cnt);

    // ---- iterations 1..9
    float dum0, dum1;
    for (int k = 1; k < 10; ++k) {
        pair_pass<false>(s_sh, g_sh, wsx, wbx, wsy_t, wby_t, sub, gj,
                         tsp, tbl, dum0, dum1);
        REDUCE16(tsp); REDUCE16(tbl);
        d = base - beta * (tsp * rnsp) - gamma * (tbl * rnbl);
        s = 1.0f / (1.0f + __builtin_amdgcn_exp2f(-d * LOG2E));
        if (k < 9) {
            float* buf = (k & 1) ? s1 : s0;
            publish_sync_restage(t, bid, s, (unsigned)(k + 1), buf,
                                 s_sh, s_out, cnt);
        } else {
            if (sub == 0) out[j] = s;     // softmax(q)[1] = sigmoid(d)
        }
    }
}

}  // namespace

extern "C" void kernel_launch(void* const* d_in, const int* in_sizes, int n_in,
                              void* d_out, int out_size, void* d_ws, size_t ws_size,
                              hipStream_t stream) {
    const float* inp = (const float*)d_in[0];
    const float* spw = (const float*)d_in[1];
    const float* blw = (const float*)d_in[2];
    const float* cmw = (const float*)d_in[3];
    float* s0 = (float*)d_ws;                       // SPAD*4 = 3328 floats
    float* s1 = s0 + SPAD * 4;
    unsigned* cnt = (unsigned*)((char*)d_ws + 2 * SPAD * 16);  // byte 26624
    float* out = (float*)d_out;

    // counters: 8 group + root + 8 flags, 256B-strided
    hipMemsetAsync(cnt, 0, (2 * NGRP + 1) * CPAD * sizeof(unsigned), stream);
    crf_all<<<dim3(NBLK), dim3(NTHR), 0, stream>>>(inp, spw, blw, cmw,
                                                   s0, s1, cnt, out);
}

// Round 8
// 84.819 us; speedup vs baseline: 6.3474x; 1.4841x over previous
//
#include <hip/hip_runtime.h>

// CRF-RNN (C=2) on 56x56, 10 iterations in ONE kernel, plain launch.
// 392 blocks x 256 thr (4 waves), ~30KB LDS -> all blocks co-resident
// (needs <=2 blocks/CU of LDS+waves; have 160KB/32-wave capacity).
//
// Math: s = sigmoid(q1-q0); per iter t_sp=K_sp@s, t_bl=K_bl@s;
// d = (2u-1) - alpha - beta*t_sp/n_sp - gamma*t_bl/n_bl. Kernels factored
// separably: k_sp = wsy[row]*wsx[x], k_bl = wby[row]*wbx[x]*exp2(C3*dg^2);
// geometric tables built once in LDS (iteration-invariant).
//
// Sync v5 -- ZERO-SENTINEL FLOW CONTROL (no counters, no tree, no fences):
// every published value is a sigmoid output, strictly in (0,1) -> bit
// pattern never 0x0. Nine distinct publish buffers (one per sync), all
// pre-zeroed by ONE hipMemsetAsync per launch. Publish = 8 relaxed agent
// stores (execute at LLC, sc1, no cache maintenance). Consume = reload the
// 3136-float field with global_load_dwordx4 sc0 sc1 (LLC-fresh, coalesced,
// 13 in flight) and re-poll until no element is 0.0. Critical path ~= one
// store RT + one poll RT at the LLC, vs ~6 serialized RTs for a counter tree.

namespace {

constexpr int NPIX = 3136;
constexpr int WIMG = 56;
constexpr int LPJ  = 32;              // lanes cooperating per j
constexpr int JPB  = 8;               // j-pixels per block
constexpr int NBLK = NPIX / JPB;      // 392 blocks
constexpr int NTHR = JPB * LPJ;       // 256 threads (4 waves)
constexpr int NQ   = NPIX / 4;        // 784 quads
constexpr int NBUF = 9;               // publish buffers (syncs after iters 0..8)

constexpr float LOG2E = 1.4426950408889634f;
constexpr float C1 = -LOG2E / 18.0f;      // spatial:   exp2(C1*d^2)
constexpr float C2 = -LOG2E / 51200.0f;   // bilateral spatial factor
constexpr float C3 = -LOG2E / 6.0f;       // bilateral intensity factor

// Strided-quad pair pass: lane sub handles quads {sub, sub+32, ...} (25
// trips, last masked). Per quad: 4-elem partials folded by row weights.
template <bool FIRST>
__device__ __forceinline__ void pair_pass(
    const float4* s4, const float4* g4,
    const float* wsx, const float* wbx,     // this j's rows: tbl + jl*56
    const float* wsy, const float* wby,
    int sub, float gj,
    float& tsp_o, float& tbl_o, float& nsp_o, float& nbl_o)
{
    float tsp = 0.f, tbl = 0.f, nsp = 0.f, nbl = 0.f;
    int mq  = sub;                        // global quad index
    int row = (sub >= 28) ? 2 : (sub >= 14 ? 1 : 0);
    int xq  = sub - 14 * row;             // quad col (0..13)
    for (int k = 0; k < 25; ++k) {
        if (mq < NQ) {
            const float4 sv = s4[mq];
            const float4 gv = g4[mq];
            const float4 wsv = *(const float4*)(wsx + xq * 4);
            const float4 wbv = *(const float4*)(wbx + xq * 4);
            float rS = 0.f, rB = 0.f, nS = 0.f, nB = 0.f;
#pragma unroll
            for (int e = 0; e < 4; ++e) {
                const float se = ((const float*)&sv)[e];
                const float ge = ((const float*)&gv)[e];
                const float ws = ((const float*)&wsv)[e];
                const float wb = ((const float*)&wbv)[e];
                const float dg = ge - gj;
                const float edg = __builtin_amdgcn_exp2f((dg * C3) * dg);
                rS = fmaf(ws, se, rS);
                const float p = wb * edg;
                rB = fmaf(p, se, rB);
                if (FIRST) { nS += ws; nB += p; }
            }
            const float wy = wsy[row], wbr = wby[row];
            tsp = fmaf(wy, rS, tsp);
            tbl = fmaf(wbr, rB, tbl);
            if (FIRST) { nsp = fmaf(wy, nS, nsp); nbl = fmaf(wbr, nB, nbl); }
        }
        mq += 32;
        xq += 4; row += 2;                // +32 quads = +2 rows + 4 quads
        if (xq >= 14) { xq -= 14; row += 1; }
    }
    tsp_o = tsp; tbl_o = tbl;
    if (FIRST) { nsp_o = nsp; nbl_o = nbl; }
}

#define REDUCE32(v) \
    { v += __shfl_xor(v, 1); v += __shfl_xor(v, 2); v += __shfl_xor(v, 4); \
      v += __shfl_xor(v, 8); v += __shfl_xor(v, 16); }

// Publish this block's 8 s-values to buf (zero-initialized, single writer per
// slot), then poll-reload the whole field until fully nonzero, into LDS.
__device__ __forceinline__ void publish_sync_restage(
    int t, int bid, float s,
    float* buf, float4* s_sh, float* s_out_lds)
{
    if ((t & (LPJ - 1)) == 0) s_out_lds[t >> 5] = s;   // j-leaders -> LDS
    __syncthreads();                                    // pair_pass done too
    if (t < 64) {                                       // comm wave only
        if (t < JPB)
            __hip_atomic_store(&buf[bid * JPB + t], s_out_lds[t],
                               __ATOMIC_RELAXED, __HIP_MEMORY_SCOPE_AGENT);
        const float4* src = (const float4*)buf;
        float4 vv[12]; float4 vt;
        for (;;) {
#pragma unroll
            for (int q = 0; q < 12; ++q)
                asm volatile("global_load_dwordx4 %0, %1, off sc0 sc1"
                             : "=&v"(vv[q]) : "v"(src + q * 64 + t));
            if (t < 16)
                asm volatile("global_load_dwordx4 %0, %1, off sc0 sc1"
                             : "=&v"(vt) : "v"(src + 768 + t));
            asm volatile("s_waitcnt vmcnt(0)" ::: "memory");
            float mn = 1.0f;                            // s values are >0
#pragma unroll
            for (int q = 0; q < 12; ++q)
                mn = fminf(mn, fminf(fminf(vv[q].x, vv[q].y),
                                     fminf(vv[q].z, vv[q].w)));
            if (t < 16)
                mn = fminf(mn, fminf(fminf(vt.x, vt.y), fminf(vt.z, vt.w)));
            if (!__any(mn == 0.0f)) break;              // all 3136 published
            __builtin_amdgcn_s_sleep(1);
        }
#pragma unroll
        for (int q = 0; q < 12; ++q) s_sh[q * 64 + t] = vv[q];
        if (t < 16) s_sh[768 + t] = vt;
    }
    __syncthreads();                                    // compute waves resume
}

__global__ __launch_bounds__(NTHR) void crf_all(
    const float* __restrict__ inp,
    const float* __restrict__ spw, const float* __restrict__ blw,
    const float* __restrict__ cmw,
    float* sbufs,                          // NBUF x NPIX, pre-zeroed
    float* __restrict__ out)
{
    __shared__ float4 s_sh[NQ];           // current s (restaged per sync)
    __shared__ float4 g_sh[NQ];           // gray*255 (iteration-invariant)
    __shared__ float  wsx_t[JPB * 56];    // exp2(C1*(xj-x')^2) per local j
    __shared__ float  wbx_t[JPB * 56];    // exp2(C2*(xj-x')^2)
    __shared__ float  wsy_t[56];          // exp2(C1*(yj-y')^2) (yj same all j)
    __shared__ float  wby_t[56];          // exp2(C2*(yj-y')^2)
    __shared__ float  s_out[JPB];

    const int t   = threadIdx.x;
    const int bid = blockIdx.x;
    const int sub = t & (LPJ - 1);
    const int jl  = t >> 5;
    const int j   = bid * JPB + jl;

    const int xj0 = (bid * JPB) % WIMG;   // 8 j's: same row, consecutive x
    const int yj  = (bid * JPB) / WIMG;
    const float uj = inp[j];
    const float gj = inp[NPIX + j] * 255.0f;

    // collapse the 2x2 weight matrices to 3 scalars
    const float e0 = cmw[2] - cmw[0];
    const float e1 = cmw[3] - cmw[1];
    const float alpha = e0 * (spw[0] + blw[0]) + e1 * (spw[2] + blw[2]);
    const float beta  = e0 * (spw[1] - spw[0]) + e1 * (spw[3] - spw[2]);
    const float gamma = e0 * (blw[1] - blw[0]) + e1 * (blw[3] - blw[2]);

    // build weight tables (iteration-invariant)
    for (int idx = t; idx < JPB * 56; idx += NTHR) {
        const int tjl = idx / 56, xp = idx - tjl * 56;
        const float dd = (float)(xj0 + tjl - xp);
        const float d2 = dd * dd;
        wsx_t[idx] = __builtin_amdgcn_exp2f(C1 * d2);
        wbx_t[idx] = __builtin_amdgcn_exp2f(C2 * d2);
    }
    if (t < 56) {
        const float dd = (float)(yj - t);
        const float d2 = dd * dd;
        wsy_t[t] = __builtin_amdgcn_exp2f(C1 * d2);
        wby_t[t] = __builtin_amdgcn_exp2f(C2 * d2);
    }
    // stage u (iter-0 s) and g*255 into LDS
    {
        const float4* u4 = (const float4*)inp;
        const float4* gg = (const float4*)(inp + NPIX);
        for (int m = t; m < NQ; m += NTHR) {
            s_sh[m] = u4[m];
            float4 g = gg[m];
            g.x *= 255.0f; g.y *= 255.0f; g.z *= 255.0f; g.w *= 255.0f;
            g_sh[m] = g;
        }
    }
    __syncthreads();

    const float* wsx = wsx_t + jl * 56;
    const float* wbx = wbx_t + jl * 56;

    // ---- iteration 0: s = u (unaries), also accumulates norms
    float tsp, tbl, nsp, nbl;
    pair_pass<true>(s_sh, g_sh, wsx, wbx, wsy_t, wby_t, sub, gj,
                    tsp, tbl, nsp, nbl);
    REDUCE32(tsp); REDUCE32(tbl); REDUCE32(nsp); REDUCE32(nbl);
    const float rnsp = 1.0f / nsp;
    const float rnbl = 1.0f / nbl;
    const float base = 2.0f * uj - 1.0f - alpha;

    float d = base - beta * (tsp * rnsp) - gamma * (tbl * rnbl);
    float s = 1.0f / (1.0f + __builtin_amdgcn_exp2f(-d * LOG2E));
    publish_sync_restage(t, bid, s, sbufs, s_sh, s_out);

    // ---- iterations 1..9
    float dum0, dum1;
    for (int k = 1; k < 10; ++k) {
        pair_pass<false>(s_sh, g_sh, wsx, wbx, wsy_t, wby_t, sub, gj,
                         tsp, tbl, dum0, dum1);
        REDUCE32(tsp); REDUCE32(tbl);
        d = base - beta * (tsp * rnsp) - gamma * (tbl * rnbl);
        s = 1.0f / (1.0f + __builtin_amdgcn_exp2f(-d * LOG2E));
        if (k < 9) {
            publish_sync_restage(t, bid, s, sbufs + k * NPIX, s_sh, s_out);
        } else {
            if (sub == 0) out[j] = s;     // softmax(q)[1] = sigmoid(d)
        }
    }
}

}  // namespace

extern "C" void kernel_launch(void* const* d_in, const int* in_sizes, int n_in,
                              void* d_out, int out_size, void* d_ws, size_t ws_size,
                              hipStream_t stream) {
    const float* inp = (const float*)d_in[0];
    const float* spw = (const float*)d_in[1];
    const float* blw = (const float*)d_in[2];
    const float* cmw = (const float*)d_in[3];
    float* sbufs = (float*)d_ws;          // 9 x 3136 floats, zero = "not yet"
    float* out = (float*)d_out;

    hipMemsetAsync(sbufs, 0, NBUF * NPIX * sizeof(float), stream);
    crf_all<<<dim3(NBLK), dim3(NTHR), 0, stream>>>(inp, spw, blw, cmw,
                                                   sbufs, out);
}

// Round 9
// 76.568 us; speedup vs baseline: 7.0315x; 1.1078x over previous
//
#include <hip/hip_runtime.h>

// CRF-RNN (C=2) on 56x56, 10 iterations in ONE kernel, plain launch.
// 392 blocks x 256 thr (4 waves), ~60KB LDS -> 2 blocks/CU, all co-resident.
//
// Math: s = sigmoid(q1-q0); d = (2u-1) - alpha - beta*t_sp/n_sp - gamma*t_bl/n_bl.
//  * spatial kernel separable: t_sp via 56-tap row conv + column fold;
//    n_sp = Sx(xj)*Sy(yj) exactly.
//  * bilateral: theta_beta=3 -> exp(-dg^2/6) < 3e-19 for |dg|>16 of 255.
//    Pixels counting-sorted by intensity ONCE (deterministic, stable,
//    atomic-free); per j only the +-16-bucket band is visited (~390 pairs).
//  * norms s-independent: computed at iter 0, reciprocals in registers.
//
// Sync (proven round 8): zero-sentinel flow control. Sigmoid outputs are
// never 0.0f; 9 distinct pre-zeroed publish buffers; publish = 8 relaxed
// agent stores (LLC-coherent, no L2 maintenance); consume = re-read field
// with global_load_dwordx4 sc0 sc1 until fully nonzero.

namespace {

constexpr int NPIX = 3136;
constexpr int WIMG = 56;
constexpr int JPB  = 8;               // j-pixels per block
constexpr int NBLK = NPIX / JPB;      // 392 blocks
constexpr int NTHR = 256;             // 4 waves
constexpr int NBUF = 9;               // publish buffers
constexpr int BAND = 16;              // intensity band (buckets)

constexpr float LOG2E = 1.4426950408889634f;
constexpr float C1 = -LOG2E / 18.0f;      // spatial exponent coeff
constexpr float C2 = -LOG2E / 51200.0f;   // bilateral spatial coeff
constexpr float C3 = -LOG2E / 6.0f;       // bilateral intensity coeff

// LDS pool layout (bytes, 16-aligned)
constexpr int O_SSH  = 0;         // float[3136]  s, linear image order
constexpr int O_SSRT = 12544;     // float[3136]  s, intensity-sorted (init: g tmp)
constexpr int O_XYV  = 25088;     // float[3136]  x+64y, sorted (init: H lo)
constexpr int O_GSRT = 37632;     // float[3136]  g, sorted      (init: H hi)
constexpr int O_RANK = 50176;     // u16[3136]    orig -> sorted pos
constexpr int O_OFF  = 56448;     // u32[257]     bucket offsets
constexpr int O_W1C  = 57488;     // float[4][128] shifted spatial tables
constexpr int O_WSY  = 59536;     // float[56]    column weights
constexpr int O_ROWC = 59776;     // float[56*9]  row-conv (padded stride 9)
constexpr int O_SOUT = 61792;     // float[8]
constexpr int POOLSZ = 61824;

#define REDUCE32(v) \
    { v += __shfl_xor(v, 1); v += __shfl_xor(v, 2); v += __shfl_xor(v, 4); \
      v += __shfl_xor(v, 8); v += __shfl_xor(v, 16); }

__global__ __launch_bounds__(NTHR) void crf_all(
    const float* __restrict__ inp,
    const float* __restrict__ spw, const float* __restrict__ blw,
    const float* __restrict__ cmw,
    float* sbufs, float* __restrict__ out)
{
    __shared__ __align__(16) unsigned char pool[POOLSZ];
    float*  s_sh    = (float*)(pool + O_SSH);
    float4* s_sh4   = (float4*)(pool + O_SSH);
    float*  s_srt   = (float*)(pool + O_SSRT);
    float*  xyv_srt = (float*)(pool + O_XYV);
    float*  g_srt   = (float*)(pool + O_GSRT);
    unsigned short* rank = (unsigned short*)(pool + O_RANK);
    unsigned*       offs = (unsigned*)(pool + O_OFF);
    float*  W1c   = (float*)(pool + O_W1C);
    float*  wsy   = (float*)(pool + O_WSY);
    float*  rowc  = (float*)(pool + O_ROWC);
    float*  s_out = (float*)(pool + O_SOUT);
    unsigned short* H  = (unsigned short*)(pool + O_XYV);  // init union (25088B)
    unsigned*       Hz = (unsigned*)(pool + O_XYV);
    float*  tmpg = s_srt;                                   // init alias

    const int t   = threadIdx.x;
    const int bid = blockIdx.x;
    const int sub = t & 31;
    const int jl  = t >> 5;
    const int j   = bid * JPB + jl;
    const int xj0 = (bid * JPB) % WIMG;
    const int yj  = (bid * JPB) / WIMG;
    const int XJ  = xj0 + jl;
    const float xjf = (float)XJ, yjf = (float)yj;

    const float uj = inp[j];
    const float gj = inp[NPIX + j] * 255.0f;

    // collapse the 2x2 weight matrices to 3 scalars
    const float e0 = cmw[2] - cmw[0];
    const float e1 = cmw[3] - cmw[1];
    const float alpha = e0 * (spw[0] + blw[0]) + e1 * (spw[2] + blw[2]);
    const float beta  = e0 * (spw[1] - spw[0]) + e1 * (spw[3] - spw[2]);
    const float gamma = e0 * (blw[1] - blw[0]) + e1 * (blw[3] - blw[2]);

    // ---- I0: stage u and g; build W1 tables; zero H
    {
        const float4* u4 = (const float4*)inp;
        const float4* g4 = (const float4*)(inp + NPIX);
        float4* tg4 = (float4*)tmpg;
        for (int m = t; m < NPIX / 4; m += NTHR) {
            s_sh4[m] = u4[m];
            float4 g = g4[m];
            g.x *= 255.f; g.y *= 255.f; g.z *= 255.f; g.w *= 255.f;
            tg4[m] = g;
        }
        for (int i = t; i < 512; i += NTHR) {       // W1c[r][i]=exp2(C1(56+r-i)^2)
            int r = i >> 7, ii = i & 127;
            float dd = (float)(56 + r - ii);
            W1c[i] = __builtin_amdgcn_exp2f(C1 * dd * dd);
        }
        if (t < 56) {
            float dd = (float)(yj - t);
            wsy[t] = __builtin_amdgcn_exp2f(C1 * dd * dd);
        }
        for (int i = t; i < 6272; i += NTHR) Hz[i] = 0u;
    }
    __syncthreads();
    // ---- I1: per-chunk histogram (49 chunks x 64 px, single-owner rows)
    if (t < 49) {
        unsigned short* Hr = H + t * 256;
        const int mb = t * 64;
        for (int i = 0; i < 64; ++i) {
            int b = (int)tmpg[mb + i]; b = b > 255 ? 255 : b;
            Hr[b] = (unsigned short)(Hr[b] + 1);
        }
    }
    __syncthreads();
    // ---- I2: column prefix per bucket; totals -> offs[b]
    {
        unsigned run = 0;
        for (int c = 0; c < 49; ++c) {
            unsigned short v = H[c * 256 + t];
            H[c * 256 + t] = (unsigned short)run;
            run += v;
        }
        offs[t] = run;
    }
    __syncthreads();
    // ---- I3: exclusive scan offs[0..255] (one wave, 4 buckets/lane)
    if (t < 64) {
        unsigned v0 = offs[4 * t], v1 = offs[4 * t + 1];
        unsigned v2 = offs[4 * t + 2], v3 = offs[4 * t + 3];
        unsigned sum = v0 + v1 + v2 + v3;
        unsigned sc = sum;
        for (int d = 1; d < 64; d <<= 1) {
            unsigned n = __shfl_up(sc, d);
            if (t >= d) sc += n;
        }
        unsigned base = sc - sum;
        offs[4 * t] = base;
        offs[4 * t + 1] = base + v0;
        offs[4 * t + 2] = base + v0 + v1;
        offs[4 * t + 3] = base + v0 + v1 + v2;
        if (t == 63) offs[256] = sc;               // = 3136
    }
    __syncthreads();
    // ---- I4: stable deterministic ranks
    if (t < 49) {
        unsigned short* Hr = H + t * 256;
        const int mb = t * 64;
        for (int i = 0; i < 64; ++i) {
            int b = (int)tmpg[mb + i]; b = b > 255 ? 255 : b;
            rank[mb + i] = (unsigned short)(offs[b] + Hr[b]);
            Hr[b] = (unsigned short)(Hr[b] + 1);
        }
    }
    __syncthreads();
    // ---- I5: fill sorted pos/intensity (overwrites H region)
    for (int m = t; m < NPIX; m += NTHR) {
        int r = rank[m];
        int y = m / WIMG;
        int x = m - y * WIMG;
        xyv_srt[r] = (float)(x + 64 * y);          // exact in fp32
        g_srt[r] = tmpg[m];
    }
    __syncthreads();
    // ---- I6: s_srt for iteration 0 (tmpg region now dead)
    for (int m = t; m < NPIX; m += NTHR) s_srt[rank[m]] = s_sh[m];
    __syncthreads();

    // n_sp = Sx*Sy (exact separable)
    float sx, sy;
    {
        float dd = xjf - (float)sub;
        sx = __builtin_amdgcn_exp2f(C1 * dd * dd);
        if (sub + 32 < 56) {
            float d2 = xjf - (float)(sub + 32);
            sx += __builtin_amdgcn_exp2f(C1 * d2 * d2);
        }
        REDUCE32(sx);
        dd = yjf - (float)sub;
        sy = __builtin_amdgcn_exp2f(C1 * dd * dd);
        if (sub + 32 < 56) {
            float d2 = yjf - (float)(sub + 32);
            sy += __builtin_amdgcn_exp2f(C1 * d2 * d2);
        }
        REDUCE32(sy);
    }
    const float rnsp = 1.0f / (sx * sy);

    int bj = (int)gj; bj = bj > 255 ? 255 : bj;
    const int blo = (int)offs[bj < BAND ? 0 : bj - BAND];
    const int bhi = (int)offs[(bj + BAND > 255 ? 255 : bj + BAND) + 1];

    // separable spatial: row conv (448 outputs over 256 thr) + column fold
    auto spatial = [&]() -> float {
        const int yA = t >> 3, jl2 = t & 7;
        const int XJ2 = xj0 + jl2;
        const int r = XJ2 & 3;
        const float4* R = (const float4*)(W1c + r * 128 + (56 + r - XJ2));
        {
            const float4* S = s_sh4 + yA * 14;
            float acc = 0.f;
#pragma unroll
            for (int q = 0; q < 14; ++q) {
                float4 w = R[q], sv = S[q];
                acc = fmaf(w.x, sv.x, acc); acc = fmaf(w.y, sv.y, acc);
                acc = fmaf(w.z, sv.z, acc); acc = fmaf(w.w, sv.w, acc);
            }
            rowc[yA * 9 + jl2] = acc;
        }
        const int yB = yA + 32;
        if (yB < 56) {
            const float4* S = s_sh4 + yB * 14;
            float acc = 0.f;
#pragma unroll
            for (int q = 0; q < 14; ++q) {
                float4 w = R[q], sv = S[q];
                acc = fmaf(w.x, sv.x, acc); acc = fmaf(w.y, sv.y, acc);
                acc = fmaf(w.z, sv.z, acc); acc = fmaf(w.w, sv.w, acc);
            }
            rowc[yB * 9 + jl2] = acc;
        }
        __syncthreads();
        float part = wsy[sub] * rowc[sub * 9 + jl];
        if (sub + 32 < 56)
            part = fmaf(wsy[sub + 32], rowc[(sub + 32) * 9 + jl], part);
        REDUCE32(part);
        return part;
    };

    // publish + zero-sentinel sync + restage (linear + sorted)
    auto publish_sync = [&](float s, float* buf) {
        if (sub == 0) s_out[jl] = s;
        __syncthreads();
        if (t < 64) {
            if (t < JPB)
                __hip_atomic_store(&buf[bid * JPB + t], s_out[t],
                                   __ATOMIC_RELAXED, __HIP_MEMORY_SCOPE_AGENT);
            const float4* src = (const float4*)buf;
            float4 vv[12]; float4 vt;
            for (;;) {
#pragma unroll
                for (int q = 0; q < 12; ++q)
                    asm volatile("global_load_dwordx4 %0, %1, off sc0 sc1"
                                 : "=&v"(vv[q]) : "v"(src + q * 64 + t));
                if (t < 16)
                    asm volatile("global_load_dwordx4 %0, %1, off sc0 sc1"
                                 : "=&v"(vt) : "v"(src + 768 + t));
                asm volatile("s_waitcnt vmcnt(0)" ::: "memory");
                float mn = 1.0f;
#pragma unroll
                for (int q = 0; q < 12; ++q)
                    mn = fminf(mn, fminf(fminf(vv[q].x, vv[q].y),
                                         fminf(vv[q].z, vv[q].w)));
                if (t < 16)
                    mn = fminf(mn, fminf(fminf(vt.x, vt.y), fminf(vt.z, vt.w)));
                if (!__any(mn == 0.0f)) break;
                __builtin_amdgcn_s_sleep(1);
            }
#pragma unroll
            for (int q = 0; q < 12; ++q) s_sh4[q * 64 + t] = vv[q];
            if (t < 16) s_sh4[768 + t] = vt;
        }
        __syncthreads();
        for (int m = t; m < NPIX; m += NTHR) s_srt[rank[m]] = s_sh[m];
        __syncthreads();
    };

    const float base = 2.0f * uj - 1.0f - alpha;
    float rnbl, s;

    // ---- iteration 0 (s = u), also accumulates n_bl over the band
    {
        float tsp = spatial();
        float acc = 0.f, nacc = 0.f;
        for (int p = blo + sub; p < bhi; p += 32) {
            float xyv = xyv_srt[p], gv = g_srt[p], sv = s_srt[p];
            float yi = floorf(xyv * 0.015625f);
            float xi = fmaf(-64.f, yi, xyv);
            float ux = xi - xjf, vy = yi - yjf;
            float r2 = fmaf(ux, ux, vy * vy);
            float dg = gv - gj;
            float arg = fmaf(dg * C3, dg, r2 * C2);
            float w = __builtin_amdgcn_exp2f(arg);
            acc = fmaf(w, sv, acc);
            nacc += w;
        }
        REDUCE32(acc); REDUCE32(nacc);
        rnbl = 1.0f / nacc;
        float d = base - beta * (tsp * rnsp) - gamma * (acc * rnbl);
        s = 1.0f / (1.0f + __builtin_amdgcn_exp2f(-d * LOG2E));
    }
    publish_sync(s, sbufs);

    // ---- iterations 1..9
    for (int k = 1; k < 10; ++k) {
        float tsp = spatial();
        float acc = 0.f;
        for (int p = blo + sub; p < bhi; p += 32) {
            float xyv = xyv_srt[p], gv = g_srt[p], sv = s_srt[p];
            float yi = floorf(xyv * 0.015625f);
            float xi = fmaf(-64.f, yi, xyv);
            float ux = xi - xjf, vy = yi - yjf;
            float r2 = fmaf(ux, ux, vy * vy);
            float dg = gv - gj;
            float arg = fmaf(dg * C3, dg, r2 * C2);
            float w = __builtin_amdgcn_exp2f(arg);
            acc = fmaf(w, sv, acc);
        }
        REDUCE32(acc);
        float d = base - beta * (tsp * rnsp) - gamma * (acc * rnbl);
        s = 1.0f / (1.0f + __builtin_amdgcn_exp2f(-d * LOG2E));
        if (k < 9) publish_sync(s, sbufs + k * NPIX);
        else if (sub == 0) out[j] = s;   // softmax(q)[1] = sigmoid(d)
    }
}

}  // namespace

extern "C" void kernel_launch(void* const* d_in, const int* in_sizes, int n_in,
                              void* d_out, int out_size, void* d_ws, size_t ws_size,
                              hipStream_t stream) {
    const float* inp = (const float*)d_in[0];
    const float* spw = (const float*)d_in[1];
    const float* blw = (const float*)d_in[2];
    const float* cmw = (const float*)d_in[3];
    float* sbufs = (float*)d_ws;          // 9 x 3136 floats, zero = "not yet"
    float* out = (float*)d_out;

    hipMemsetAsync(sbufs, 0, NBUF * NPIX * sizeof(float), stream);
    crf_all<<<dim3(NBLK), dim3(NTHR), 0, stream>>>(inp, spw, blw, cmw,
                                                   sbufs, out);
}